// Round 4
// baseline (155.301 us; speedup 1.0000x reference)
//
#include <hip/hip_runtime.h>
#include <hip/hip_bf16.h>
#include <cstddef>

#define B_ 8
#define H_ 12
#define N_ 2048
#define D_ 64
#define M_ 256
#define BH_ (B_*H_)

typedef __attribute__((ext_vector_type(8))) short short8v;
typedef __attribute__((ext_vector_type(4))) float f32x4;
typedef __attribute__((address_space(3))) unsigned int lds_u32_t;
typedef __attribute__((address_space(1))) const unsigned int glb_u32_t;

static __device__ __forceinline__ float4 ld4(const float* p){ return *(const float4*)p; }

static __device__ __forceinline__ unsigned short f2bf(float x){
    union { float f; unsigned int u; } v; v.f = x;
    unsigned int r = v.u + 0x7FFFu + ((v.u >> 16) & 1u);
    return (unsigned short)(r >> 16);
}
static __device__ __forceinline__ unsigned int pack2(float a, float b){
    return (unsigned int)f2bf(a) | ((unsigned int)f2bf(b) << 16);
}
static __device__ __forceinline__ void gload_lds16(const void* g, void* l){
    __builtin_amdgcn_global_load_lds((glb_u32_t*)g, (lds_u32_t*)l, 16, 0, 0);
}

// ---------------- K0b: Dct fp32 -> DctB bf16 [256][2048] + DctT bf16 [2048][256]
__global__ __launch_bounds__(256)
void dct_prep_kernel(const float* __restrict__ Dct, unsigned short* __restrict__ DctB,
                     unsigned short* __restrict__ DctT)
{
    __shared__ __align__(16) unsigned short T[64*72];
    const int n0 = blockIdx.x * 64, m0 = blockIdx.y * 64;
    const int tid = threadIdx.x;
    const int m = tid >> 2, ng = tid & 3;
    unsigned short h[16];
    #pragma unroll
    for (int j = 0; j < 4; ++j) {
        const float4 t = ld4(Dct + (size_t)(m0+m)*N_ + n0 + ng*16 + j*4);
        h[4*j+0]=f2bf(t.x); h[4*j+1]=f2bf(t.y); h[4*j+2]=f2bf(t.z); h[4*j+3]=f2bf(t.w);
    }
    unsigned int w[8];
    #pragma unroll
    for (int j = 0; j < 8; ++j) w[j] = (unsigned int)h[2*j] | ((unsigned int)h[2*j+1]<<16);
    unsigned short* db = DctB + (size_t)(m0+m)*N_ + n0 + ng*16;
    *(uint4*)db = *(uint4*)&w[0];
    *(uint4*)(db+8) = *(uint4*)&w[4];
    #pragma unroll
    for (int j = 0; j < 16; ++j) T[(ng*16+j)*72 + m] = h[j];
    __syncthreads();
    const int n = tid >> 2, mg = tid & 3;
    uint4 a  = *(uint4*)&T[n*72 + mg*16];
    uint4 b2 = *(uint4*)&T[n*72 + mg*16 + 8];
    unsigned short* dt = DctT + (size_t)(n0+n)*M_ + m0 + mg*16;
    *(uint4*)dt = a; *(uint4*)(dt+8) = b2;
}

// ---------------- K1: Qd/Kd/Vd = DctB @ (scaled/masked X), MFMA bf16 ----------
// 1D grid 576 (XCD-swizzled), 256 threads (4 waves), tile 128m x 64d, BK=64.
// 3-buffer LDS pipeline; NO vmcnt drain in the main loop: A-stage completion is
// guaranteed transitively (STAGE_A issued before LOAD_B in vmcnt FIFO; the
// compiler's counted wait for LOAD_B's regs in WRITE_B implies STAGE_A done).
__global__ __launch_bounds__(256, 2)
void gemm_qkv(const float* __restrict__ Q, const float* __restrict__ K,
              const float* __restrict__ V, const float* __restrict__ mask,
              const unsigned short* __restrict__ DctB,
              float* __restrict__ Qd, float* __restrict__ Kd, float* __restrict__ Vd)
{
    __shared__ __align__(16) unsigned short Asw[3][128*64];  // 48 KB
    __shared__ __align__(16) unsigned short Bsw[3][64*64];   // 24 KB
    // XCD swizzle: 576 = 8 * 72; consecutive work-ids land on one XCD chunk.
    const int wg = blockIdx.x;
    const int id = (wg & 7) * 72 + (wg >> 3);
    const int ms = id & 1;
    const int bhz = id >> 1;          // 0..287
    const int bh = bhz % 96;
    const int tz = bhz / 96;
    const int b = bh / H_;
    const float scale = 0.35355339059327373f;
    const float* X; float* Y; float smul; int um;
    if (tz==0)      { X=Q; Y=Qd; smul=scale; um=0; }
    else if (tz==1) { X=K; Y=Kd; smul=scale; um=1; }
    else            { X=V; Y=Vd; smul=1.0f;  um=1; }
    X += (size_t)bh*N_*D_;
    Y += (size_t)bh*M_*D_ + (size_t)ms*128*D_;
    const int m0 = ms*128;

    const int tid  = threadIdx.x;
    const int lane = tid & 63, wave = tid >> 6;
    const int d0   = (tid & 31)*2, kseg = tid >> 5;
    const int bswz = ((d0>>1)&7)<<4;
    const int ar = lane >> 3, as = lane & 7;
    const int ac = as ^ ar;   // pre-swizzled source chunk for A staging

    f32x4 acc[2][4];
    #pragma unroll
    for (int i = 0; i < 2; ++i)
        #pragma unroll
        for (int j = 0; j < 4; ++j) { acc[i][j].x=0.f; acc[i][j].y=0.f; acc[i][j].z=0.f; acc[i][j].w=0.f; }

    float2 xr[2][8];
    float  mr[2][8];

    const unsigned short* abase = DctB + (size_t)(m0 + wave*32 + ar) * N_ + ac*8;

    #define STAGE_A(BUF, K0) do {                                             \
        _Pragma("unroll")                                                     \
        for (int i_ = 0; i_ < 4; ++i_) {                                      \
            const int R_ = wave*32 + i_*8;                                    \
            gload_lds16(abase + (size_t)(i_*8)*N_ + (K0),                     \
                        (char*)&Asw[BUF][0] + R_*128);                        \
        }                                                                     \
    } while(0)

    #define LOAD_B(SET, K0) do {                                              \
        const float* xp_ = X + (size_t)((K0) + kseg*8) * D_ + d0;             \
        const float* mp_ = mask + (size_t)b*N_ + (K0) + kseg*8;               \
        _Pragma("unroll")                                                     \
        for (int i_ = 0; i_ < 8; ++i_) {                                      \
            xr[SET][i_] = *(const float2*)(xp_ + i_*D_);                      \
            mr[SET][i_] = mp_[i_];                                            \
        }                                                                     \
    } while(0)

    #define WRITE_B(SET, BUF) do {                                            \
        float fa_[8], fb_[8];                                                 \
        _Pragma("unroll")                                                     \
        for (int i_ = 0; i_ < 8; ++i_) {                                      \
            const float f_ = um ? smul*mr[SET][i_] : smul;                    \
            fa_[i_] = xr[SET][i_].x * f_; fb_[i_] = xr[SET][i_].y * f_;       \
        }                                                                     \
        uint4 w0_, w1_;                                                       \
        w0_.x=pack2(fa_[0],fa_[1]); w0_.y=pack2(fa_[2],fa_[3]);               \
        w0_.z=pack2(fa_[4],fa_[5]); w0_.w=pack2(fa_[6],fa_[7]);               \
        w1_.x=pack2(fb_[0],fb_[1]); w1_.y=pack2(fb_[2],fb_[3]);               \
        w1_.z=pack2(fb_[4],fb_[5]); w1_.w=pack2(fb_[6],fb_[7]);               \
        *(uint4*)((char*)&Bsw[BUF][0] + d0*128     + ((kseg*16) ^ bswz)) = w0_; \
        *(uint4*)((char*)&Bsw[BUF][0] + (d0+1)*128 + ((kseg*16) ^ bswz)) = w1_; \
    } while(0)

    #define COMPUTE(BUF) do {                                                 \
        _Pragma("unroll")                                                     \
        for (int kh_ = 0; kh_ < 2; ++kh_) {                                   \
            const int colb_ = kh_*64 + (lane>>4)*16;                          \
            short8v a_[2], bb_[4];                                            \
            _Pragma("unroll")                                                 \
            for (int mf_ = 0; mf_ < 2; ++mf_) {                               \
                const int r_ = wave*32 + mf_*16 + (lane&15);                  \
                a_[mf_] = *(const short8v*)((char*)&Asw[BUF][0] + r_*128 + (colb_ ^ ((r_&7)<<4))); \
            }                                                                 \
            _Pragma("unroll")                                                 \
            for (int nf_ = 0; nf_ < 4; ++nf_) {                               \
                const int rr_ = nf_*16 + (lane&15);                           \
                bb_[nf_] = *(const short8v*)((char*)&Bsw[BUF][0] + rr_*128 + (colb_ ^ (((rr_>>1)&7)<<4))); \
            }                                                                 \
            _Pragma("unroll")                                                 \
            for (int mf_ = 0; mf_ < 2; ++mf_)                                 \
                _Pragma("unroll")                                             \
                for (int nf_ = 0; nf_ < 4; ++nf_)                             \
                    acc[mf_][nf_] = __builtin_amdgcn_mfma_f32_16x16x32_bf16(a_[mf_], bb_[nf_], acc[mf_][nf_], 0, 0, 0); \
        }                                                                     \
    } while(0)

    #define FENCE() asm volatile("" ::: "memory")
    #define BAR()  do { asm volatile("s_waitcnt lgkmcnt(0)" ::: "memory");    \
                        __builtin_amdgcn_sched_barrier(0);                    \
                        __builtin_amdgcn_s_barrier(); } while(0)

    // prologue: stage steps 0 and 1
    STAGE_A(0, 0);   FENCE();  LOAD_B(0, 0);
    STAGE_A(1, 64);  FENCE();  LOAD_B(1, 64);
    WRITE_B(0, 0);   // counted vmcnt wait here also guarantees STAGE_A(buf0) done
    BAR();

    // main loop: steps 0..29, period-6 unroll so all indices are literals
    #define BODY(IDX) do {                                                    \
        const int t_ = tb + (IDX);                                            \
        STAGE_A(((IDX)+2)%3, (t_+2)*64);                                      \
        FENCE();                                                              \
        LOAD_B((IDX)&1, (t_+2)*64);                                           \
        COMPUTE((IDX)%3);                                                     \
        WRITE_B(((IDX)+1)&1, ((IDX)+1)%3);                                    \
        BAR();                                                                \
    } while(0)

    for (int tb = 0; tb < 30; tb += 6) {
        BODY(0); BODY(1); BODY(2); BODY(3); BODY(4); BODY(5);
    }
    // tail: t=30, t=31  (30%3==0, 31%3==1, 31&1==1)
    COMPUTE(0);
    WRITE_B(1, 1);
    BAR();
    COMPUTE(1);

    // epilogue
    #pragma unroll
    for (int mf = 0; mf < 2; ++mf)
        #pragma unroll
        for (int nf = 0; nf < 4; ++nf)
            #pragma unroll
            for (int r = 0; r < 4; ++r) {
                const int m = wave*32 + mf*16 + (lane>>4)*4 + r;
                const int d = nf*16 + (lane&15);
                Y[(size_t)m*D_ + d] = acc[mf][nf][r];
            }
    #undef STAGE_A
    #undef LOAD_B
    #undef WRITE_B
    #undef COMPUTE
    #undef FENCE
    #undef BAR
    #undef BODY
}

// ---------------- K2: fused energy -> softmax -> ctx (fp32), bf16 transposed out
__global__ __launch_bounds__(256)
void attn_kernel(const float* __restrict__ Qd, const float* __restrict__ Kd,
                 const float* __restrict__ Vd, unsigned short* __restrict__ CtxT)
{
    __shared__ __align__(16) float S[M_][D_];    // 64 KB
    const int mt = blockIdx.x;
    const int bh = blockIdx.y;
    const float* qd = Qd + (size_t)bh * M_ * D_;
    const float* kd = Kd + (size_t)bh * M_ * D_;
    const float* vd = Vd + (size_t)bh * M_ * D_;

    const int tid = threadIdx.x;
    const int r = tid >> 2, sub = tid & 3;
    const int m = mt * 64 + r;

    float q[64];
    #pragma unroll
    for (int g = 0; g < 16; ++g) {
        const float4 t = ld4(qd + (size_t)m * D_ + g*4);
        q[4*g+0] = t.x; q[4*g+1] = t.y; q[4*g+2] = t.z; q[4*g+3] = t.w;
    }

    #pragma unroll
    for (int it = 0; it < 16; ++it) {
        const int i = tid + it*256;
        const int k = i >> 4, g = i & 15;
        const float4 t = ld4(kd + (size_t)i * 4);
        *(float4*)(&S[k][(g ^ (k & 3)) * 4]) = t;
    }
    __syncthreads();

    float e[64];
    #pragma unroll
    for (int kk = 0; kk < 64; ++kk) {
        const int k = kk*4 + sub;
        float acc = 0.f;
        #pragma unroll
        for (int g = 0; g < 16; ++g) {
            const float4 t = ld4(&S[k][(g ^ sub) * 4]);
            acc = fmaf(q[4*g+0], t.x, acc);
            acc = fmaf(q[4*g+1], t.y, acc);
            acc = fmaf(q[4*g+2], t.z, acc);
            acc = fmaf(q[4*g+3], t.w, acc);
        }
        e[kk] = acc;
    }

    float mx = e[0];
    #pragma unroll
    for (int kk = 1; kk < 64; ++kk) mx = fmaxf(mx, e[kk]);
    mx = fmaxf(mx, __shfl_xor(mx, 1));
    mx = fmaxf(mx, __shfl_xor(mx, 2));
    float sum = 0.f;
    #pragma unroll
    for (int kk = 0; kk < 64; ++kk) { e[kk] = __expf(e[kk] - mx); sum += e[kk]; }
    sum += __shfl_xor(sum, 1);
    sum += __shfl_xor(sum, 2);
    const float inv = 1.0f / sum;

    __syncthreads();
    #pragma unroll
    for (int it = 0; it < 16; ++it) {
        const int i = tid + it*256;
        const int k = i >> 4, g = i & 15;
        const float4 t = ld4(vd + (size_t)i * 4);
        *(float4*)(&S[k][(g ^ (k & 3)) * 4]) = t;
    }
    __syncthreads();

    float c[64] = {};
    #pragma unroll
    for (int kk = 0; kk < 64; ++kk) {
        const int k = kk*4 + sub;
        const float a = e[kk];
        #pragma unroll
        for (int g = 0; g < 16; ++g) {
            const float4 t = ld4(&S[k][(g ^ sub) * 4]);
            c[4*g+0] = fmaf(a, t.x, c[4*g+0]);
            c[4*g+1] = fmaf(a, t.y, c[4*g+1]);
            c[4*g+2] = fmaf(a, t.z, c[4*g+2]);
            c[4*g+3] = fmaf(a, t.w, c[4*g+3]);
        }
    }
    #pragma unroll
    for (int d = 0; d < 64; ++d) {
        c[d] += __shfl_xor(c[d], 1);
        c[d] += __shfl_xor(c[d], 2);
    }

    __syncthreads();
    unsigned short* T = (unsigned short*)&S[0][0];   // [64 d][72 m] ushorts
    #pragma unroll
    for (int g = 0; g < 16; ++g) {
        const int d = sub*16 + g;
        T[d*72 + r] = f2bf(c[d]*inv);
    }
    __syncthreads();
    const int d2 = tid >> 2, mg = tid & 3;
    uint4 w0 = *(uint4*)&T[d2*72 + mg*16];
    uint4 w1 = *(uint4*)&T[d2*72 + mg*16 + 8];
    unsigned short* dst = CtxT + (size_t)bh*D_*M_ + (size_t)d2*M_ + mt*64 + mg*16;
    *(uint4*)dst = w0; *(uint4*)(dst+8) = w1;
}

// ---------------- K3: x = DctT @ ctx_t^T, MFMA bf16 ------------------------
__global__ __launch_bounds__(128, 2)
void gemm_out(const unsigned short* __restrict__ DctT, const unsigned short* __restrict__ CtxT,
              float* __restrict__ Out)
{
    __shared__ __align__(16) unsigned short Asw[128*64];
    __shared__ __align__(16) unsigned short Bsw[64*64];
    const int nt = blockIdx.x, bh = blockIdx.y;
    const int n0 = nt*128;
    const unsigned short* ct = CtxT + (size_t)bh*D_*M_;
    float* out = Out + (size_t)bh*N_*D_;
    const int tid = threadIdx.x;
    const int lane = tid & 63, wave = tid >> 6;

    f32x4 acc[4][4];
    #pragma unroll
    for (int i = 0; i < 4; ++i)
        #pragma unroll
        for (int j = 0; j < 4; ++j) { acc[i][j].x=0.f; acc[i][j].y=0.f; acc[i][j].z=0.f; acc[i][j].w=0.f; }

    for (int step = 0; step < 4; ++step) {
        const int k0 = step*64;
        if (step) __syncthreads();
        const int ch = tid & 7;
        #pragma unroll
        for (int rr = 0; rr < 8; ++rr) {
            const int r = (tid>>3) + rr*16;
            const uint4 v = *(const uint4*)(DctT + (size_t)(n0+r)*M_ + k0 + ch*8);
            *(uint4*)((char*)Asw + r*128 + ((ch*16) ^ ((r&7)<<4))) = v;
        }
        #pragma unroll
        for (int rr = 0; rr < 4; ++rr) {
            const int d = (tid>>3) + rr*16;
            const uint4 v = *(const uint4*)(ct + (size_t)d*M_ + k0 + ch*8);
            *(uint4*)((char*)Bsw + d*128 + ((ch*16) ^ (((d>>1)&7)<<4))) = v;
        }
        __syncthreads();
        #pragma unroll
        for (int kh = 0; kh < 2; ++kh) {
            const int colb = kh*64 + (lane>>4)*16;
            short8v a[4], bb[4];
            #pragma unroll
            for (int mf = 0; mf < 4; ++mf) {
                const int r = wave*64 + mf*16 + (lane&15);
                a[mf] = *(const short8v*)((char*)Asw + r*128 + (colb ^ ((r&7)<<4)));
            }
            #pragma unroll
            for (int nf = 0; nf < 4; ++nf) {
                const int r = nf*16 + (lane&15);
                bb[nf] = *(const short8v*)((char*)Bsw + r*128 + (colb ^ (((r>>1)&7)<<4)));
            }
            #pragma unroll
            for (int mf = 0; mf < 4; ++mf)
                #pragma unroll
                for (int nf = 0; nf < 4; ++nf)
                    acc[mf][nf] = __builtin_amdgcn_mfma_f32_16x16x32_bf16(a[mf], bb[nf], acc[mf][nf], 0, 0, 0);
        }
    }
    #pragma unroll
    for (int mf = 0; mf < 4; ++mf)
        #pragma unroll
        for (int nf = 0; nf < 4; ++nf)
            #pragma unroll
            for (int r = 0; r < 4; ++r) {
                const int n = n0 + wave*64 + mf*16 + (lane>>4)*4 + r;
                const int d = nf*16 + (lane&15);
                out[(size_t)n*D_ + d] = acc[mf][nf][r];
            }
}

extern "C" void kernel_launch(void* const* d_in, const int* in_sizes, int n_in,
                              void* d_out, int out_size, void* d_ws, size_t ws_size,
                              hipStream_t stream) {
    const float* Q    = (const float*)d_in[0];
    const float* K    = (const float*)d_in[1];
    const float* V    = (const float*)d_in[2];
    const float* mask = (const float*)d_in[3];
    const float* Dct  = (const float*)d_in[4];
    float* out = (float*)d_out;

    const size_t per = (size_t)BH_ * M_ * D_;          // 1,572,864
    float* wsf = (float*)d_ws;
    float* Qd = wsf;
    float* Kd = Qd + per;
    float* Vd = Kd + per;
    unsigned short* CtxT = (unsigned short*)(Vd + per);  // per ushorts
    unsigned short* DctB = CtxT + per;                   // 524288
    unsigned short* DctT = DctB + (size_t)M_ * N_;       // 524288

    dct_prep_kernel<<<dim3(N_/64, M_/64), 256, 0, stream>>>(Dct, DctB, DctT);
    gemm_qkv<<<dim3(576), 256, 0, stream>>>(Q, K, V, mask, DctB, Qd, Kd, Vd);
    attn_kernel<<<dim3(M_/64, BH_), 256, 0, stream>>>(Qd, Kd, Vd, CtxT);
    gemm_out<<<dim3(N_/128, BH_), 128, 0, stream>>>(DctT, CtxT, out);
}